// Round 10
// baseline (124.989 us; speedup 1.0000x reference)
//
#include <hip/hip_runtime.h>
#include <math.h>

typedef _Float16 h4  __attribute__((ext_vector_type(4)));
typedef _Float16 h8  __attribute__((ext_vector_type(8)));
typedef __fp16   p2  __attribute__((ext_vector_type(2)));   // cvt_pkrtz / fdot2 operand type
typedef float    f4  __attribute__((ext_vector_type(4)));
typedef float    f16x __attribute__((ext_vector_type(16)));

#define NPAIR (8*256*256)
#define NTILE32 (NPAIR/32)        // 16384 tiles of 32 pairs
#define BLOCKS 2048
#define ITERS (NTILE32/(BLOCKS*4))  // 2 tiles per wave

// 32x32x16 f16 MFMA (gfx950): C/D: col=lane&31, row=(reg&3)+8*(reg>>2)+4*(lane>>5)
// A/B (verified R18 on HW): m/n=lane&31, k=8*(lane>>5)+j
#define MFMA(a,b,c) __builtin_amdgcn_mfma_f32_32x32x16_f16((a),(b),(c),0,0,0)

#define LOG2E 1.44269504088896340736f
#define LN2   0.69314718055994530942f

// Physical->logical channel permutation for 64-wide layers built from two 32x32
// C/D tiles: physical P = 32*mt + (g&3)+8*(g>>2)+4*hi  holds logical channel
// kappa = 32*mt + 16*(g>>3) + 8*hi + (g&7).  With B-frag chunk c built as
// pk8(C[mt=c>>1] regs 8*(c&1)..+7), slot (c,hi,j) then holds logical 16c+8hi+j
// == the MFMA k-index -> layers chain in-register with identity k-axis.
__device__ __forceinline__ int pi64(int P)
{
    int mt = P >> 5, r = P & 31;
    int hi = (r >> 2) & 1;
    int g  = (r & 3) + 4*(r >> 3);
    return 32*mt + 16*(g >> 3) + 8*hi + (g & 7);
}

// A-fragment pool (h8 units):
// [0,128)      W1^T  frags [mt][lane]: elem j: k=8*(lane>>5)+j;
//              k<9 -> W1[k][pi(32mt+(lane&31))]*log2e; k==9 -> b1*log2e; else 0
// [128,1152)   W2'^T frags [(enc*2+mt)*4+c][lane]: k=16c+8*(lane>>5)+j;
//              val = W2[k][P]*fg[enc][P]*ln2, P=pi(32mt+(lane&31))
// [1152,2176)  Wg1^T frags [mt*8+cc][lane]: in=64*(cc>>2)+16*(cc&3)+8*(lane>>5)+j;
//              val = Wg1[in][P]*log2e
__device__ h8 g_frag[2176];
// Epilogue consts in C/D order: flat = base + mt*32 + hi*16 + g:
// [0,128) E-init (enc major)  [128,192) bg1*log2e  [192,256) (Wg2[1]-Wg2[0])*ln2
// [256,320) ln_g*Wo
__device__ float g_cst[320];
__device__ float g_cc[2];         // C0 = sum ln_b*Wo, C1 = sum ln_g*Wo

__global__ void prep_kernel(const float* __restrict__ W1, const float* __restrict__ b1,
                            const float* __restrict__ W2, const float* __restrict__ b2,
                            const float* __restrict__ fgam, const float* __restrict__ fbet,
                            const float* __restrict__ Wg1, const float* __restrict__ bg1,
                            const float* __restrict__ Wg2,
                            const float* __restrict__ ln_g, const float* __restrict__ ln_b,
                            const float* __restrict__ Wo)
{
    int idx = blockIdx.x * 256 + threadIdx.x;
    if (idx < 2176) {
        h8 v;
        if (idx < 128) {
            int mt = idx >> 6, L = idx & 63;
            int hi = L >> 5, m = L & 31;
            int P = pi64(32*mt + m);
#pragma unroll
            for (int j = 0; j < 8; ++j) {
                int k = 8*hi + j;
                float x = (k < 9) ? W1[k*64 + P] : (k == 9 ? b1[P] : 0.f);
                v[j] = (_Float16)(x * LOG2E);
            }
        } else if (idx < 1152) {
            int z = idx - 128; int f = z >> 6, L = z & 63;
            int c = f & 3, mt = (f >> 2) & 1, enc = f >> 3;
            int hi = L >> 5, m = L & 31;
            int P = pi64(32*mt + m);
            float fgv = fgam[enc*64 + P] * LN2;
#pragma unroll
            for (int j = 0; j < 8; ++j) {
                int k = 16*c + 8*hi + j;
                v[j] = (_Float16)(W2[k*64 + P] * fgv);
            }
        } else {
            int z = idx - 1152; int f = z >> 6, L = z & 63;
            int cc = f & 7, mt = f >> 3;
            int hi = L >> 5, m = L & 31;
            int P = pi64(32*mt + m);
#pragma unroll
            for (int j = 0; j < 8; ++j) {
                int in = 64*(cc >> 2) + 16*(cc & 3) + 8*hi + j;
                v[j] = (_Float16)(Wg1[in*64 + P] * LOG2E);
            }
        }
        g_frag[idx] = v;
    } else if (idx >= 4352 && idx < 4416) {
        int k = idx - 4352;
        float c0 = ln_b[k]*Wo[k], c1 = ln_g[k]*Wo[k];
#pragma unroll
        for (int s = 1; s < 64; s <<= 1) {
            c0 += __shfl_xor(c0, s);
            c1 += __shfl_xor(c1, s);
        }
        if (k == 0) { g_cc[0] = c0; g_cc[1] = c1; }
    } else if (idx >= 4608 && idx < 4928) {
        int c = idx - 4608;
        float v;
        if (c < 128) {
            int enc = c >> 6, w = c & 63;
            int mt = w >> 5, hi = (w >> 4) & 1, g = w & 15;
            int P = pi64(32*mt + (g & 3) + 8*(g >> 2) + 4*hi);
            v = fmaf(b2[P], fgam[enc*64 + P], fbet[enc*64 + P]);
        } else if (c < 192) {
            int w = c - 128, mt = w >> 5, hi = (w >> 4) & 1, g = w & 15;
            int P = pi64(32*mt + (g & 3) + 8*(g >> 2) + 4*hi);
            v = bg1[P] * LOG2E;
        } else if (c < 256) {
            int w = c - 192, mt = w >> 5, hi = (w >> 4) & 1, g = w & 15;
            int P = pi64(32*mt + (g & 3) + 8*(g >> 2) + 4*hi);
            v = (Wg2[2*P+1] - Wg2[2*P]) * LN2;
        } else {
            int w = c - 256, mt = w >> 5, hi = (w >> 4) & 1, g = w & 15;
            int P = pi64(32*mt + (g & 3) + 8*(g >> 2) + 4*hi);
            v = ln_g[P] * Wo[P];
        }
        g_cst[c] = v;
    }
}

// x' = x*log2e (folded into weights): x'/(1+2^-x') = log2e*silu(x); trailing ln2
// folded into the consumer. 2 trans + 2 VALU per element.
__device__ __forceinline__ f16x xsig16(f16x v)
{
#pragma unroll
    for (int i = 0; i < 16; ++i)
        v[i] = v[i] * __builtin_amdgcn_rcpf(1.f + __builtin_amdgcn_exp2f(-v[i]));
    return v;
}

template<int B>
__device__ __forceinline__ h8 pk8(const f16x& v)   // C/D regs B..B+7 -> h8 B-frag
{
    p2 a = __builtin_amdgcn_cvt_pkrtz(v[B+0], v[B+1]);
    p2 b = __builtin_amdgcn_cvt_pkrtz(v[B+2], v[B+3]);
    p2 c = __builtin_amdgcn_cvt_pkrtz(v[B+4], v[B+5]);
    p2 d = __builtin_amdgcn_cvt_pkrtz(v[B+6], v[B+7]);
    h8 r;
    r[0]=a[0]; r[1]=a[1]; r[2]=b[0]; r[3]=b[1];
    r[4]=c[0]; r[5]=c[1]; r[6]=d[0]; r[7]=d[1];
    return r;
}

__device__ __forceinline__ unsigned pu(p2 v)
{
    union { p2 p; unsigned u; } x; x.p = v; return x.u;
}

__device__ __forceinline__ h8 h8w(unsigned a, unsigned b, unsigned c, unsigned d)
{
    union { unsigned u[4]; h8 h; } x;
    x.u[0] = a; x.u[1] = b; x.u[2] = c; x.u[3] = d;
    return x.h;
}

__device__ __forceinline__ f16x ld16(const float* p)
{
    const f4* q = (const f4*)p;
    f4 a = q[0], b = q[1], c = q[2], d = q[3];
    f16x r;
#pragma unroll
    for (int i = 0; i < 4; ++i) { r[i] = a[i]; r[4+i] = b[i]; r[8+i] = c[i]; r[12+i] = d[i]; }
    return r;
}

// 8-channel f16 dot via v_dot2_f32_f16 (2 ch/instr, f32 accumulate)
__device__ __forceinline__ float dot8h(h8 a, h8 b, float acc)
{
    union U { h8 v; p2 q[4]; } ua, ub;
    ua.v = a; ub.v = b;
#pragma unroll
    for (int i = 0; i < 4; ++i)
        acc = __builtin_amdgcn_fdot2(ua.q[i], ub.q[i], acc, false);
    return acc;
}

// per-tile feature builder (verified in R21): one doubling chain per lane
// (hb=0 cost, hb=1 angle), 4 shfl_xor(32) to exchange packed words.
__device__ __forceinline__ void feat_frags(float xc, float2 ci, float2 cj, int hb,
                                           float sc0, float sc1, h8& fb0, h8& fb1)
{
    const float dx = ci.x - cj.x, dy = ci.y - cj.y;
    const float rr = dx*dx + dy*dy;
    const float rinv = __builtin_amdgcn_rsqf(rr);
    // fast atan2(dy,dx): minimax deg-11, |err|~1e-5 (f16 feature ulp ~1e-3)
    const float ax = fabsf(dx), ay = fabsf(dy);
    const float mx = fmaxf(ax, ay), mn = fminf(ax, ay);
    const float t = mn * __builtin_amdgcn_rcpf(mx);
    const float t2 = t*t;
    float pa = fmaf(t2, -0.0117212f, 0.05265332f);
    pa = fmaf(t2, pa, -0.11643287f);
    pa = fmaf(t2, pa, 0.19354346f);
    pa = fmaf(t2, pa, -0.33262347f);
    pa = fmaf(t2, pa, 0.99997726f);
    float a = t * pa;
    a = (ay > ax) ? 1.57079632679f - a : a;
    a = (dx < 0.f) ? 3.14159265359f - a : a;
    a = __int_as_float(__float_as_int(a) | (__float_as_int(dy) & 0x80000000));
    const bool ok = rr > 0.f;                  // diagonal (i==j): angle=0
    const float ang = ok ? a : 0.f;
    const float snA = ok ? dy*rinv : 0.f;      // sin(atan2) exact
    const float csA = ok ? dx*rinv : 1.f;      // cos(atan2) exact
    const float xv  = hb ? ang : xc;
    const float sn1 = hb ? snA : __sinf(xc);
    const float cs1 = hb ? csA : __cosf(xc);
    const float sE  = hb ? sc1 : sc0;
    const float sn2 = 2.f*sn1*cs1, cs2 = fmaf(-2.f*sn1, sn1, 1.f);
    const float sn4 = 2.f*sn2*cs2, cs4 = fmaf(-2.f*sn2, sn2, 1.f);
    const float sn8 = 2.f*sn4*cs4, cs8 = fmaf(-2.f*sn4, sn4, 1.f);
    const unsigned u0 = pu(__builtin_amdgcn_cvt_pkrtz(xv*sE,  sn1*sE));
    const unsigned u1 = pu(__builtin_amdgcn_cvt_pkrtz(cs1*sE, sn2*sE));
    const unsigned u2 = pu(__builtin_amdgcn_cvt_pkrtz(cs2*sE, sn4*sE));
    const unsigned u3 = pu(__builtin_amdgcn_cvt_pkrtz(cs4*sE, sn8*sE));
    const unsigned u4 = pu(__builtin_amdgcn_cvt_pkrtz(cs8*sE, 1.0f));  // feats 8,9 (9 = bias-1)
    const unsigned sel0 = hb ? u0 : u4;
    const unsigned rw0 = __shfl_xor((int)sel0, 32);
    const unsigned rw1 = __shfl_xor((int)u1, 32);
    const unsigned rw2 = __shfl_xor((int)u2, 32);
    const unsigned rw3 = __shfl_xor((int)u3, 32);
    fb0 = hb ? h8w(rw0, 0, 0, 0) : h8w(u0, u1, u2, u3);    // cost enc
    fb1 = hb ? h8w(u4, 0, 0, 0) : h8w(rw0, rw1, rw2, rw3); // angle enc
}

// R26 = R25 (43.2us) + software pipeline of the 2 tiles/wave: iteration it+1's
// feature phase (loads + trig + pack, ~100 VALU/trans instrs, no MFMA deps) is
// computed inside iteration it's body at the minimum-liveness point (after the
// partials, E dead), and the 2-trip loop is #pragma unroll'd so the scheduler
// interleaves it into the L2/gate1 MFMA-chain bubbles (gate1 = 2x 8-deep chains
// ~250cy each; only ~2.4-3 waves/SIMD resident to cover them). Bit-exact values.
__global__ __launch_bounds__(256, 4) void fused_kernel(
    const float* __restrict__ coords, const float* __restrict__ cost,
    const float* __restrict__ lscale, const float* __restrict__ bg2,
    const float* __restrict__ gt, const float* __restrict__ bo,
    float* __restrict__ out)
{
    __shared__ __align__(16) char smem[32768 + 1536];
    const int tid = threadIdx.x;
    const int wave = tid >> 6, lane = tid & 63;
    const int pr = lane & 31, hb = lane >> 5;

    h8* wpool = (h8*)smem;                    // [0,1024) W2' frags, [1024,2048) Wg1 frags
    for (int z = tid; z < 2048; z += 256) wpool[z] = g_frag[128 + z];
    float* cpool = (float*)(smem + 32768);    // [0,128) E-init, [128,192) G-init (f32)
    for (int z = tid; z < 192; z += 256) cpool[z] = g_cst[z];
    _Float16* gwh = (_Float16*)(smem + 32768 + 768);    // 128 halfs: ln_g*Wo, frag order
    _Float16* wdh = (_Float16*)(smem + 32768 + 1024);   // 64 halfs: (Wg2[1]-Wg2[0])*ln2
    for (int z = tid; z < 128; z += 256) gwh[z] = (_Float16)g_cst[256 + z];
    for (int z = tid; z < 64;  z += 256) wdh[z] = (_Float16)g_cst[192 + z];
    __syncthreads();

    // W1^T A-frags, register-resident (8 VGPRs)
    h8 w1a0 = g_frag[lane], w1a1 = g_frag[64 + lane];
    h8 onesh;
#pragma unroll
    for (int j = 0; j < 8; ++j) onesh[j] = (_Float16)1.f;

    const float dlgb = bg2[1] - bg2[0];
    const float sc0 = __expf(lscale[0]), sc1 = __expf(lscale[1]);
    const float invT2 = __expf(-gt[0]) * LOG2E;
    const float outc = g_cc[0] + bo[0], C1 = g_cc[1];

    const int wgid = blockIdx.x*4 + wave;

    // ---- prologue: features for tile 0 ----
    h8 fb0, fb1;
    {
        const int p0 = wgid*32;
        const int bb = p0 >> 16, ii = (p0 >> 8) & 255, j0 = p0 & 255;
        const float2* cb2 = (const float2*)(coords + (bb << 9));
        feat_frags(cost[p0 + pr], cb2[ii], cb2[j0 + pr], hb, sc0, sc1, fb0, fb1);
    }

#pragma unroll
    for (int it = 0; it < ITERS; ++it) {
        const int p0 = (wgid + it*(BLOCKS*4))*32;
        // ---- L1: H' = (W1*log2e)^T @ feat^T, K=16 (10 feats + zero pad) ----
        const f16x z16 = {0.f,0.f,0.f,0.f,0.f,0.f,0.f,0.f,0.f,0.f,0.f,0.f,0.f,0.f,0.f,0.f};
        f16x H00 = MFMA(w1a0, fb0, z16);
        f16x H01 = MFMA(w1a1, fb0, z16);
        f16x H10 = MFMA(w1a0, fb1, z16);
        f16x H11 = MFMA(w1a1, fb1, z16);
        // launder pool pointers: block LICM from hoisting frags/consts into regs
        int wofs = 0; asm volatile("" : "+s"(wofs));
        const h8* wp = wpool + wofs;
        const float* cstl = cpool + wofs;
        const h8* gwf = (const h8*)gwh + wofs;
        const h8* wdf = (const h8*)wdh + wofs;
        // f16 gw frags (shared by both encoders' D partials)
        const h8 gw00 = gwf[2*hb], gw01 = gwf[2*hb+1];
        const h8 gw10 = gwf[4+2*hb], gw11 = gwf[4+2*hb+1];
        // ---- L2 enc0 ----
        H00 = xsig16(H00); H01 = xsig16(H01);
        h8 hf0 = pk8<0>(H00), hf1 = pk8<8>(H00), hf2 = pk8<0>(H01), hf3 = pk8<8>(H01);
        f16x E00 = ld16(cstl + 16*hb);
        f16x E01 = ld16(cstl + 32 + 16*hb);
        E00 = MFMA(wp[0*64+lane], hf0, E00);
        E00 = MFMA(wp[1*64+lane], hf1, E00);
        E00 = MFMA(wp[2*64+lane], hf2, E00);
        E00 = MFMA(wp[3*64+lane], hf3, E00);
        E01 = MFMA(wp[4*64+lane], hf0, E01);
        E01 = MFMA(wp[5*64+lane], hf1, E01);
        E01 = MFMA(wp[6*64+lane], hf2, E01);
        E01 = MFMA(wp[7*64+lane], hf3, E01);
        // e-frags for enc0; f32 E00/E01 die right here
        const h8 ef0 = pk8<0>(E00), ef1 = pk8<8>(E00), ef2 = pk8<0>(E01), ef3 = pk8<8>(E01);
        // enc0 partials from f16 frags (fdot2; ones-dot is exact)
        float A0 = dot8h(ef1, onesh, dot8h(ef0, onesh, 0.f))
                 + dot8h(ef3, onesh, dot8h(ef2, onesh, 0.f));
        float D0 = dot8h(ef1, gw01, dot8h(ef0, gw00, 0.f))
                 + dot8h(ef3, gw11, dot8h(ef2, gw10, 0.f));
        float Q0 = dot8h(ef1, ef1, dot8h(ef0, ef0, 0.f))
                 + dot8h(ef3, ef3, dot8h(ef2, ef2, 0.f));
        // ---- L2 enc1 ----
        H10 = xsig16(H10); H11 = xsig16(H11);
        hf0 = pk8<0>(H10); hf1 = pk8<8>(H10); hf2 = pk8<0>(H11); hf3 = pk8<8>(H11);
        f16x E10 = ld16(cstl + 64 + 16*hb);
        f16x E11 = ld16(cstl + 96 + 16*hb);
        E10 = MFMA(wp[ 8*64+lane], hf0, E10);
        E10 = MFMA(wp[ 9*64+lane], hf1, E10);
        E10 = MFMA(wp[10*64+lane], hf2, E10);
        E10 = MFMA(wp[11*64+lane], hf3, E10);
        E11 = MFMA(wp[12*64+lane], hf0, E11);
        E11 = MFMA(wp[13*64+lane], hf1, E11);
        E11 = MFMA(wp[14*64+lane], hf2, E11);
        E11 = MFMA(wp[15*64+lane], hf3, E11);
        const h8 ef4 = pk8<0>(E10), ef5 = pk8<8>(E10), ef6 = pk8<0>(E11), ef7 = pk8<8>(E11);
        // enc1 + cross partials (f32 E10/E11 die here)
        float A1 = dot8h(ef5, onesh, dot8h(ef4, onesh, 0.f))
                 + dot8h(ef7, onesh, dot8h(ef6, onesh, 0.f));
        float D1 = dot8h(ef5, gw01, dot8h(ef4, gw00, 0.f))
                 + dot8h(ef7, gw11, dot8h(ef6, gw10, 0.f));
        float Q2 = dot8h(ef5, ef5, dot8h(ef4, ef4, 0.f))
                 + dot8h(ef7, ef7, dot8h(ef6, ef6, 0.f));
        float QX = dot8h(ef5, ef1, dot8h(ef4, ef0, 0.f))
                 + dot8h(ef7, ef3, dot8h(ef6, ef2, 0.f));
        // ---- PIPELINE: next tile's features at the liveness minimum; the
        // scheduler interleaves this VALU/trans work into gate1's MFMA bubbles ----
        h8 nfb0, nfb1;
        if (it + 1 < ITERS) {
            const int pn = (wgid + (it+1)*(BLOCKS*4))*32;
            const int bbn = pn >> 16, iin = (pn >> 8) & 255, j0n = pn & 255;
            const float2* cbn = (const float2*)(coords + (bbn << 9));
            feat_frags(cost[pn + pr], cbn[iin], cbn[j0n + pr], hb, sc0, sc1, nfb0, nfb1);
        }
        // ---- gate1: K=128 = enc0 chunks 0..3 then enc1 chunks 4..7 ----
        f16x G0 = ld16(cstl + 128 + 16*hb);
        f16x G1 = ld16(cstl + 160 + 16*hb);
        G0 = MFMA(wp[1024+ 0*64+lane], ef0, G0);
        G0 = MFMA(wp[1024+ 1*64+lane], ef1, G0);
        G0 = MFMA(wp[1024+ 2*64+lane], ef2, G0);
        G0 = MFMA(wp[1024+ 3*64+lane], ef3, G0);
        G0 = MFMA(wp[1024+ 4*64+lane], ef4, G0);
        G0 = MFMA(wp[1024+ 5*64+lane], ef5, G0);
        G0 = MFMA(wp[1024+ 6*64+lane], ef6, G0);
        G0 = MFMA(wp[1024+ 7*64+lane], ef7, G0);
        G1 = MFMA(wp[1024+ 8*64+lane], ef0, G1);
        G1 = MFMA(wp[1024+ 9*64+lane], ef1, G1);
        G1 = MFMA(wp[1024+10*64+lane], ef2, G1);
        G1 = MFMA(wp[1024+11*64+lane], ef3, G1);
        G1 = MFMA(wp[1024+12*64+lane], ef4, G1);
        G1 = MFMA(wp[1024+13*64+lane], ef5, G1);
        G1 = MFMA(wp[1024+14*64+lane], ef6, G1);
        G1 = MFMA(wp[1024+15*64+lane], ef7, G1);
        G0 = xsig16(G0); G1 = xsig16(G1);
        // ---- gate2: pk G -> f16, fdot2 with wd (f16); f32 G dies here ----
        const h8 gf0 = pk8<0>(G0), gf1 = pk8<8>(G0), gf2 = pk8<0>(G1), gf3 = pk8<8>(G1);
        const h8 wd00 = wdf[2*hb], wd01 = wdf[2*hb+1];
        const h8 wd10 = wdf[4+2*hb], wd11 = wdf[4+2*hb+1];
        float part = dot8h(gf1, wd01, dot8h(gf0, wd00, 0.f))
                   + dot8h(gf3, wd11, dot8h(gf2, wd10, 0.f));
        part += __shfl_xor(part, 32);
        const float w1v = __builtin_amdgcn_rcpf(1.f + __builtin_amdgcn_exp2f(-(part + dlgb)*invT2));
        // ---- recombine partials: fu = (1-w)E0 + wE1 (never materialized) ----
        const float uv = 1.f - w1v;
        float sv = fmaf(w1v, A1 - A0, A0);
        float dt = fmaf(w1v, D1 - D0, D0);
        float sq = uv*uv*Q0 + 2.f*uv*w1v*QX + w1v*w1v*Q2;
        sv += __shfl_xor(sv, 32);
        sq += __shfl_xor(sq, 32);
        dt += __shfl_xor(dt, 32);
        const float mu = sv * (1.f/64.f);
        const float vv = sq * (1.f/64.f) - mu*mu;
        const float rs = __builtin_amdgcn_rsqf(vv + 1e-5f);
        const float o = fmaf(rs, dt - mu*C1, outc);
        if (lane < 32) out[p0 + lane] = o;
        // rotate pipeline registers
        if (it + 1 < ITERS) { fb0 = nfb0; fb1 = nfb1; }
    }
}

extern "C" void kernel_launch(void* const* d_in, const int* in_sizes, int n_in,
                              void* d_out, int out_size, void* d_ws, size_t ws_size,
                              hipStream_t stream)
{
    const float* coords = (const float*)d_in[0];
    const float* cost   = (const float*)d_in[1];
    const float* lscale = (const float*)d_in[2];
    const float* W1     = (const float*)d_in[3];
    const float* b1     = (const float*)d_in[4];
    const float* W2     = (const float*)d_in[5];
    const float* b2     = (const float*)d_in[6];
    const float* fg     = (const float*)d_in[7];
    const float* fb     = (const float*)d_in[8];
    const float* Wg1    = (const float*)d_in[9];
    const float* bg1    = (const float*)d_in[10];
    const float* Wg2    = (const float*)d_in[11];
    const float* bg2    = (const float*)d_in[12];
    const float* gt     = (const float*)d_in[13];
    const float* lng    = (const float*)d_in[14];
    const float* lnb    = (const float*)d_in[15];
    const float* Wo     = (const float*)d_in[16];
    const float* bo     = (const float*)d_in[17];
    float* out = (float*)d_out;

    prep_kernel<<<20, 256, 0, stream>>>(W1, b1, W2, b2, fg, fb, Wg1, bg1, Wg2, lng, lnb, Wo);
    fused_kernel<<<BLOCKS, 256, 0, stream>>>(coords, cost, lscale, bg2, gt, bo, out);
}

// Round 11
// 123.046 us; speedup vs baseline: 1.0158x; 1.0158x over previous
//
#include <hip/hip_runtime.h>
#include <math.h>

typedef _Float16 h4  __attribute__((ext_vector_type(4)));
typedef _Float16 h8  __attribute__((ext_vector_type(8)));
typedef __fp16   p2  __attribute__((ext_vector_type(2)));   // cvt_pkrtz / fdot2 operand type
typedef float    f4  __attribute__((ext_vector_type(4)));
typedef float    f16x __attribute__((ext_vector_type(16)));

#define NPAIR (8*256*256)
#define NTILE32 (NPAIR/32)        // 16384 tiles of 32 pairs
#define BLOCKS 2048
#define ITERS (NTILE32/(BLOCKS*4))  // 2 tiles per wave

// 32x32x16 f16 MFMA (gfx950): C/D: col=lane&31, row=(reg&3)+8*(reg>>2)+4*(lane>>5)
// A/B (verified R18 on HW): m/n=lane&31, k=8*(lane>>5)+j
#define MFMA(a,b,c) __builtin_amdgcn_mfma_f32_32x32x16_f16((a),(b),(c),0,0,0)

#define LOG2E 1.44269504088896340736f
#define LN2   0.69314718055994530942f

// Physical->logical channel permutation for 64-wide layers built from two 32x32
// C/D tiles: physical P = 32*mt + (g&3)+8*(g>>2)+4*hi  holds logical channel
// kappa = 32*mt + 16*(g>>3) + 8*hi + (g&7).  With B-frag chunk c built as
// pk8(C[mt=c>>1] regs 8*(c&1)..+7), slot (c,hi,j) then holds logical 16c+8hi+j
// == the MFMA k-index -> layers chain in-register with identity k-axis.
__device__ __forceinline__ int pi64(int P)
{
    int mt = P >> 5, r = P & 31;
    int hi = (r >> 2) & 1;
    int g  = (r & 3) + 4*(r >> 3);
    return 32*mt + 16*(g >> 3) + 8*hi + (g & 7);
}

// A-fragment pool (h8 units):
// [0,128)      W1^T  frags [mt][lane]: elem j: k=8*(lane>>5)+j;
//              k<9 -> W1[k][pi(32mt+(lane&31))]*log2e; k==9 -> b1*log2e; else 0
// [128,1152)   W2'^T frags [(enc*2+mt)*4+c][lane]: k=16c+8*(lane>>5)+j;
//              val = W2[k][P]*fg[enc][P]*ln2, P=pi(32mt+(lane&31))
// [1152,2176)  Wg1^T frags [mt*8+cc][lane]: in=64*(cc>>2)+16*(cc&3)+8*(lane>>5)+j;
//              val = Wg1[in][P]*log2e
__device__ h8 g_frag[2176];
// Epilogue consts in C/D order: flat = base + mt*32 + hi*16 + g:
// [0,128) E-init (enc major)  [128,192) bg1*log2e  [192,256) (Wg2[1]-Wg2[0])*ln2
// [256,320) ln_g*Wo
__device__ float g_cst[320];
__device__ float g_cc[2];         // C0 = sum ln_b*Wo, C1 = sum ln_g*Wo

__global__ void prep_kernel(const float* __restrict__ W1, const float* __restrict__ b1,
                            const float* __restrict__ W2, const float* __restrict__ b2,
                            const float* __restrict__ fgam, const float* __restrict__ fbet,
                            const float* __restrict__ Wg1, const float* __restrict__ bg1,
                            const float* __restrict__ Wg2,
                            const float* __restrict__ ln_g, const float* __restrict__ ln_b,
                            const float* __restrict__ Wo)
{
    int idx = blockIdx.x * 256 + threadIdx.x;
    if (idx < 2176) {
        h8 v;
        if (idx < 128) {
            int mt = idx >> 6, L = idx & 63;
            int hi = L >> 5, m = L & 31;
            int P = pi64(32*mt + m);
#pragma unroll
            for (int j = 0; j < 8; ++j) {
                int k = 8*hi + j;
                float x = (k < 9) ? W1[k*64 + P] : (k == 9 ? b1[P] : 0.f);
                v[j] = (_Float16)(x * LOG2E);
            }
        } else if (idx < 1152) {
            int z = idx - 128; int f = z >> 6, L = z & 63;
            int c = f & 3, mt = (f >> 2) & 1, enc = f >> 3;
            int hi = L >> 5, m = L & 31;
            int P = pi64(32*mt + m);
            float fgv = fgam[enc*64 + P] * LN2;
#pragma unroll
            for (int j = 0; j < 8; ++j) {
                int k = 16*c + 8*hi + j;
                v[j] = (_Float16)(W2[k*64 + P] * fgv);
            }
        } else {
            int z = idx - 1152; int f = z >> 6, L = z & 63;
            int cc = f & 7, mt = f >> 3;
            int hi = L >> 5, m = L & 31;
            int P = pi64(32*mt + m);
#pragma unroll
            for (int j = 0; j < 8; ++j) {
                int in = 64*(cc >> 2) + 16*(cc & 3) + 8*hi + j;
                v[j] = (_Float16)(Wg1[in*64 + P] * LOG2E);
            }
        }
        g_frag[idx] = v;
    } else if (idx >= 4352 && idx < 4416) {
        int k = idx - 4352;
        float c0 = ln_b[k]*Wo[k], c1 = ln_g[k]*Wo[k];
#pragma unroll
        for (int s = 1; s < 64; s <<= 1) {
            c0 += __shfl_xor(c0, s);
            c1 += __shfl_xor(c1, s);
        }
        if (k == 0) { g_cc[0] = c0; g_cc[1] = c1; }
    } else if (idx >= 4608 && idx < 4928) {
        int c = idx - 4608;
        float v;
        if (c < 128) {
            int enc = c >> 6, w = c & 63;
            int mt = w >> 5, hi = (w >> 4) & 1, g = w & 15;
            int P = pi64(32*mt + (g & 3) + 8*(g >> 2) + 4*hi);
            v = fmaf(b2[P], fgam[enc*64 + P], fbet[enc*64 + P]);
        } else if (c < 192) {
            int w = c - 128, mt = w >> 5, hi = (w >> 4) & 1, g = w & 15;
            int P = pi64(32*mt + (g & 3) + 8*(g >> 2) + 4*hi);
            v = bg1[P] * LOG2E;
        } else if (c < 256) {
            int w = c - 192, mt = w >> 5, hi = (w >> 4) & 1, g = w & 15;
            int P = pi64(32*mt + (g & 3) + 8*(g >> 2) + 4*hi);
            v = (Wg2[2*P+1] - Wg2[2*P]) * LN2;
        } else {
            int w = c - 256, mt = w >> 5, hi = (w >> 4) & 1, g = w & 15;
            int P = pi64(32*mt + (g & 3) + 8*(g >> 2) + 4*hi);
            v = ln_g[P] * Wo[P];
        }
        g_cst[c] = v;
    }
}

// x' = x*log2e (folded into weights): x'/(1+2^-x') = log2e*silu(x); trailing ln2
// folded into the consumer. 2 trans + 2 VALU per element.
__device__ __forceinline__ f16x xsig16(f16x v)
{
#pragma unroll
    for (int i = 0; i < 16; ++i)
        v[i] = v[i] * __builtin_amdgcn_rcpf(1.f + __builtin_amdgcn_exp2f(-v[i]));
    return v;
}

template<int B>
__device__ __forceinline__ h8 pk8(const f16x& v)   // C/D regs B..B+7 -> h8 B-frag
{
    p2 a = __builtin_amdgcn_cvt_pkrtz(v[B+0], v[B+1]);
    p2 b = __builtin_amdgcn_cvt_pkrtz(v[B+2], v[B+3]);
    p2 c = __builtin_amdgcn_cvt_pkrtz(v[B+4], v[B+5]);
    p2 d = __builtin_amdgcn_cvt_pkrtz(v[B+6], v[B+7]);
    h8 r;
    r[0]=a[0]; r[1]=a[1]; r[2]=b[0]; r[3]=b[1];
    r[4]=c[0]; r[5]=c[1]; r[6]=d[0]; r[7]=d[1];
    return r;
}

__device__ __forceinline__ unsigned pu(p2 v)
{
    union { p2 p; unsigned u; } x; x.p = v; return x.u;
}

__device__ __forceinline__ h8 h8w(unsigned a, unsigned b, unsigned c, unsigned d)
{
    union { unsigned u[4]; h8 h; } x;
    x.u[0] = a; x.u[1] = b; x.u[2] = c; x.u[3] = d;
    return x.h;
}

// register-launder an h8: creates a fresh def point so the scheduler cannot
// hoist consumers above this line (used to pin deferred MFMAs for liveness)
__device__ __forceinline__ h8 lndr(h8 v)
{
    union { h8 h; unsigned u[4]; } x; x.h = v;
    asm volatile("" : "+v"(x.u[0]), "+v"(x.u[1]), "+v"(x.u[2]), "+v"(x.u[3]));
    return x.h;
}

__device__ __forceinline__ f16x ld16(const float* p)
{
    const f4* q = (const f4*)p;
    f4 a = q[0], b = q[1], c = q[2], d = q[3];
    f16x r;
#pragma unroll
    for (int i = 0; i < 4; ++i) { r[i] = a[i]; r[4+i] = b[i]; r[8+i] = c[i]; r[12+i] = d[i]; }
    return r;
}

// 8-channel f16 dot via v_dot2_f32_f16 (2 ch/instr, f32 accumulate)
__device__ __forceinline__ float dot8h(h8 a, h8 b, float acc)
{
    union U { h8 v; p2 q[4]; } ua, ub;
    ua.v = a; ub.v = b;
#pragma unroll
    for (int i = 0; i < 4; ++i)
        acc = __builtin_amdgcn_fdot2(ua.q[i], ub.q[i], acc, false);
    return acc;
}

// per-tile feature builder (verified in R21): one doubling chain per lane
// (hb=0 cost, hb=1 angle), 4 shfl_xor(32) to exchange packed words.
__device__ __forceinline__ void feat_frags(float xc, float2 ci, float2 cj, int hb,
                                           float sc0, float sc1, h8& fb0, h8& fb1)
{
    const float dx = ci.x - cj.x, dy = ci.y - cj.y;
    const float rr = dx*dx + dy*dy;
    const float rinv = __builtin_amdgcn_rsqf(rr);
    // fast atan2(dy,dx): minimax deg-11, |err|~1e-5 (f16 feature ulp ~1e-3)
    const float ax = fabsf(dx), ay = fabsf(dy);
    const float mx = fmaxf(ax, ay), mn = fminf(ax, ay);
    const float t = mn * __builtin_amdgcn_rcpf(mx);
    const float t2 = t*t;
    float pa = fmaf(t2, -0.0117212f, 0.05265332f);
    pa = fmaf(t2, pa, -0.11643287f);
    pa = fmaf(t2, pa, 0.19354346f);
    pa = fmaf(t2, pa, -0.33262347f);
    pa = fmaf(t2, pa, 0.99997726f);
    float a = t * pa;
    a = (ay > ax) ? 1.57079632679f - a : a;
    a = (dx < 0.f) ? 3.14159265359f - a : a;
    a = __int_as_float(__float_as_int(a) | (__float_as_int(dy) & 0x80000000));
    const bool ok = rr > 0.f;                  // diagonal (i==j): angle=0
    const float ang = ok ? a : 0.f;
    const float snA = ok ? dy*rinv : 0.f;      // sin(atan2) exact
    const float csA = ok ? dx*rinv : 1.f;      // cos(atan2) exact
    const float xv  = hb ? ang : xc;
    const float sn1 = hb ? snA : __sinf(xc);
    const float cs1 = hb ? csA : __cosf(xc);
    const float sE  = hb ? sc1 : sc0;
    const float sn2 = 2.f*sn1*cs1, cs2 = fmaf(-2.f*sn1, sn1, 1.f);
    const float sn4 = 2.f*sn2*cs2, cs4 = fmaf(-2.f*sn2, sn2, 1.f);
    const float sn8 = 2.f*sn4*cs4, cs8 = fmaf(-2.f*sn4, sn4, 1.f);
    const unsigned u0 = pu(__builtin_amdgcn_cvt_pkrtz(xv*sE,  sn1*sE));
    const unsigned u1 = pu(__builtin_amdgcn_cvt_pkrtz(cs1*sE, sn2*sE));
    const unsigned u2 = pu(__builtin_amdgcn_cvt_pkrtz(cs2*sE, sn4*sE));
    const unsigned u3 = pu(__builtin_amdgcn_cvt_pkrtz(cs4*sE, sn8*sE));
    const unsigned u4 = pu(__builtin_amdgcn_cvt_pkrtz(cs8*sE, 1.0f));  // feats 8,9 (9 = bias-1)
    const unsigned sel0 = hb ? u0 : u4;
    const unsigned rw0 = __shfl_xor((int)sel0, 32);
    const unsigned rw1 = __shfl_xor((int)u1, 32);
    const unsigned rw2 = __shfl_xor((int)u2, 32);
    const unsigned rw3 = __shfl_xor((int)u3, 32);
    fb0 = hb ? h8w(rw0, 0, 0, 0) : h8w(u0, u1, u2, u3);    // cost enc
    fb1 = hb ? h8w(u4, 0, 0, 0) : h8w(rw0, rw1, rw2, rw3); // angle enc
}

// R27 = R26 (41.6us) with accumulator-liveness surgery, bit-exact reorder:
// cross-round data (block dur 15.6us, 2.67 rounds) shows only ~3 blocks/CU
// resident despite LDS/bounds allowing 4 -> unified regfile (arch+acc) >128.
// Peak was H00..H11 all computed up front (64 acc regs) with H10/H11 held
// live through L2-enc0, plus gw frags (16) held across both partials.
// (a) enc1's L1 MFMAs deferred until after enc0 partials (hold fb1=8 regs
//     instead of H10/H11=32; launder pins them); (b) gw frags reloaded per
//     partials section via laundered pointer (no CSE; +4 LDS reads/tile).
// Est. peak ~116 < 128 -> 4 waves/SIMD -> exactly 2 block rounds.
__global__ __launch_bounds__(256, 4) void fused_kernel(
    const float* __restrict__ coords, const float* __restrict__ cost,
    const float* __restrict__ lscale, const float* __restrict__ bg2,
    const float* __restrict__ gt, const float* __restrict__ bo,
    float* __restrict__ out)
{
    __shared__ __align__(16) char smem[32768 + 1536];
    const int tid = threadIdx.x;
    const int wave = tid >> 6, lane = tid & 63;
    const int pr = lane & 31, hb = lane >> 5;

    h8* wpool = (h8*)smem;                    // [0,1024) W2' frags, [1024,2048) Wg1 frags
    for (int z = tid; z < 2048; z += 256) wpool[z] = g_frag[128 + z];
    float* cpool = (float*)(smem + 32768);    // [0,128) E-init, [128,192) G-init (f32)
    for (int z = tid; z < 192; z += 256) cpool[z] = g_cst[z];
    _Float16* gwh = (_Float16*)(smem + 32768 + 768);    // 128 halfs: ln_g*Wo, frag order
    _Float16* wdh = (_Float16*)(smem + 32768 + 1024);   // 64 halfs: (Wg2[1]-Wg2[0])*ln2
    for (int z = tid; z < 128; z += 256) gwh[z] = (_Float16)g_cst[256 + z];
    for (int z = tid; z < 64;  z += 256) wdh[z] = (_Float16)g_cst[192 + z];
    __syncthreads();

    // W1^T A-frags, register-resident (8 VGPRs)
    h8 w1a0 = g_frag[lane], w1a1 = g_frag[64 + lane];
    h8 onesh;
#pragma unroll
    for (int j = 0; j < 8; ++j) onesh[j] = (_Float16)1.f;

    const float dlgb = bg2[1] - bg2[0];
    const float sc0 = __expf(lscale[0]), sc1 = __expf(lscale[1]);
    const float invT2 = __expf(-gt[0]) * LOG2E;
    const float outc = g_cc[0] + bo[0], C1 = g_cc[1];

    const int wgid = blockIdx.x*4 + wave;

    // ---- prologue: features for tile 0 ----
    h8 fb0, fb1;
    {
        const int p0 = wgid*32;
        const int bb = p0 >> 16, ii = (p0 >> 8) & 255, j0 = p0 & 255;
        const float2* cb2 = (const float2*)(coords + (bb << 9));
        feat_frags(cost[p0 + pr], cb2[ii], cb2[j0 + pr], hb, sc0, sc1, fb0, fb1);
    }

#pragma unroll
    for (int it = 0; it < ITERS; ++it) {
        const int p0 = (wgid + it*(BLOCKS*4))*32;
        const f16x z16 = {0.f,0.f,0.f,0.f,0.f,0.f,0.f,0.f,0.f,0.f,0.f,0.f,0.f,0.f,0.f,0.f};
        // launder pool pointers: block LICM from hoisting frags/consts into regs
        int wofs = 0; asm volatile("" : "+s"(wofs));
        const h8* wp = wpool + wofs;
        const float* cstl = cpool + wofs;
        const h8* wdf = (const h8*)wdh + wofs;
        // ---- L1 enc0 only (H10/H11 deferred: 32 acc regs off the peak) ----
        f16x H00 = MFMA(w1a0, fb0, z16);
        f16x H01 = MFMA(w1a1, fb0, z16);
        // ---- L2 enc0 ----
        H00 = xsig16(H00); H01 = xsig16(H01);
        h8 hf0 = pk8<0>(H00), hf1 = pk8<8>(H00), hf2 = pk8<0>(H01), hf3 = pk8<8>(H01);
        f16x E00 = ld16(cstl + 16*hb);
        f16x E01 = ld16(cstl + 32 + 16*hb);
        E00 = MFMA(wp[0*64+lane], hf0, E00);
        E00 = MFMA(wp[1*64+lane], hf1, E00);
        E00 = MFMA(wp[2*64+lane], hf2, E00);
        E00 = MFMA(wp[3*64+lane], hf3, E00);
        E01 = MFMA(wp[4*64+lane], hf0, E01);
        E01 = MFMA(wp[5*64+lane], hf1, E01);
        E01 = MFMA(wp[6*64+lane], hf2, E01);
        E01 = MFMA(wp[7*64+lane], hf3, E01);
        // e-frags for enc0; f32 E00/E01 die right here
        const h8 ef0 = pk8<0>(E00), ef1 = pk8<8>(E00), ef2 = pk8<0>(E01), ef3 = pk8<8>(E01);
        // enc0 partials from f16 frags (fdot2; ones-dot is exact); gw loaded
        // locally via laundered ptr -> lifetime ends with this block
        float A0, D0, Q0;
        {
            int og = 0; asm volatile("" : "+s"(og));
            const h8* g = (const h8*)gwh + og;
            const h8 gw00 = g[2*hb], gw01 = g[2*hb+1];
            const h8 gw10 = g[4+2*hb], gw11 = g[4+2*hb+1];
            A0 = dot8h(ef1, onesh, dot8h(ef0, onesh, 0.f))
               + dot8h(ef3, onesh, dot8h(ef2, onesh, 0.f));
            D0 = dot8h(ef1, gw01, dot8h(ef0, gw00, 0.f))
               + dot8h(ef3, gw11, dot8h(ef2, gw10, 0.f));
            Q0 = dot8h(ef1, ef1, dot8h(ef0, ef0, 0.f))
               + dot8h(ef3, ef3, dot8h(ef2, ef2, 0.f));
        }
        // ---- L1 enc1 (deferred; launder pins it below enc0's section) ----
        fb1 = lndr(fb1);
        f16x H10 = MFMA(w1a0, fb1, z16);
        f16x H11 = MFMA(w1a1, fb1, z16);
        // ---- L2 enc1 ----
        H10 = xsig16(H10); H11 = xsig16(H11);
        hf0 = pk8<0>(H10); hf1 = pk8<8>(H10); hf2 = pk8<0>(H11); hf3 = pk8<8>(H11);
        f16x E10 = ld16(cstl + 64 + 16*hb);
        f16x E11 = ld16(cstl + 96 + 16*hb);
        E10 = MFMA(wp[ 8*64+lane], hf0, E10);
        E10 = MFMA(wp[ 9*64+lane], hf1, E10);
        E10 = MFMA(wp[10*64+lane], hf2, E10);
        E10 = MFMA(wp[11*64+lane], hf3, E10);
        E11 = MFMA(wp[12*64+lane], hf0, E11);
        E11 = MFMA(wp[13*64+lane], hf1, E11);
        E11 = MFMA(wp[14*64+lane], hf2, E11);
        E11 = MFMA(wp[15*64+lane], hf3, E11);
        const h8 ef4 = pk8<0>(E10), ef5 = pk8<8>(E10), ef6 = pk8<0>(E11), ef7 = pk8<8>(E11);
        // enc1 + cross partials (f32 E10/E11 die here); gw reloaded locally
        float A1, D1, Q2, QX;
        {
            int og = 0; asm volatile("" : "+s"(og));
            const h8* g = (const h8*)gwh + og;
            const h8 gw00 = g[2*hb], gw01 = g[2*hb+1];
            const h8 gw10 = g[4+2*hb], gw11 = g[4+2*hb+1];
            A1 = dot8h(ef5, onesh, dot8h(ef4, onesh, 0.f))
               + dot8h(ef7, onesh, dot8h(ef6, onesh, 0.f));
            D1 = dot8h(ef5, gw01, dot8h(ef4, gw00, 0.f))
               + dot8h(ef7, gw11, dot8h(ef6, gw10, 0.f));
            Q2 = dot8h(ef5, ef5, dot8h(ef4, ef4, 0.f))
               + dot8h(ef7, ef7, dot8h(ef6, ef6, 0.f));
            QX = dot8h(ef5, ef1, dot8h(ef4, ef0, 0.f))
               + dot8h(ef7, ef3, dot8h(ef6, ef2, 0.f));
        }
        // ---- PIPELINE: next tile's features at the liveness minimum; the
        // scheduler interleaves this VALU/trans work into gate1's MFMA bubbles ----
        h8 nfb0, nfb1;
        if (it + 1 < ITERS) {
            const int pn = (wgid + (it+1)*(BLOCKS*4))*32;
            const int bbn = pn >> 16, iin = (pn >> 8) & 255, j0n = pn & 255;
            const float2* cbn = (const float2*)(coords + (bbn << 9));
            feat_frags(cost[pn + pr], cbn[iin], cbn[j0n + pr], hb, sc0, sc1, nfb0, nfb1);
        }
        // ---- gate1: K=128 = enc0 chunks 0..3 then enc1 chunks 4..7 ----
        f16x G0 = ld16(cstl + 128 + 16*hb);
        f16x G1 = ld16(cstl + 160 + 16*hb);
        G0 = MFMA(wp[1024+ 0*64+lane], ef0, G0);
        G0 = MFMA(wp[1024+ 1*64+lane], ef1, G0);
        G0 = MFMA(wp[1024+ 2*64+lane], ef2, G0);
        G0 = MFMA(wp[1024+ 3*64+lane], ef3, G0);
        G0 = MFMA(wp[1024+ 4*64+lane], ef4, G0);
        G0 = MFMA(wp[1024+ 5*64+lane], ef5, G0);
        G0 = MFMA(wp[1024+ 6*64+lane], ef6, G0);
        G0 = MFMA(wp[1024+ 7*64+lane], ef7, G0);
        G1 = MFMA(wp[1024+ 8*64+lane], ef0, G1);
        G1 = MFMA(wp[1024+ 9*64+lane], ef1, G1);
        G1 = MFMA(wp[1024+10*64+lane], ef2, G1);
        G1 = MFMA(wp[1024+11*64+lane], ef3, G1);
        G1 = MFMA(wp[1024+12*64+lane], ef4, G1);
        G1 = MFMA(wp[1024+13*64+lane], ef5, G1);
        G1 = MFMA(wp[1024+14*64+lane], ef6, G1);
        G1 = MFMA(wp[1024+15*64+lane], ef7, G1);
        G0 = xsig16(G0); G1 = xsig16(G1);
        // ---- gate2: pk G -> f16, fdot2 with wd (f16); f32 G dies here ----
        const h8 gf0 = pk8<0>(G0), gf1 = pk8<8>(G0), gf2 = pk8<0>(G1), gf3 = pk8<8>(G1);
        const h8 wd00 = wdf[2*hb], wd01 = wdf[2*hb+1];
        const h8 wd10 = wdf[4+2*hb], wd11 = wdf[4+2*hb+1];
        float part = dot8h(gf1, wd01, dot8h(gf0, wd00, 0.f))
                   + dot8h(gf3, wd11, dot8h(gf2, wd10, 0.f));
        part += __shfl_xor(part, 32);
        const float w1v = __builtin_amdgcn_rcpf(1.f + __builtin_amdgcn_exp2f(-(part + dlgb)*invT2));
        // ---- recombine partials: fu = (1-w)E0 + wE1 (never materialized) ----
        const float uv = 1.f - w1v;
        float sv = fmaf(w1v, A1 - A0, A0);
        float dt = fmaf(w1v, D1 - D0, D0);
        float sq = uv*uv*Q0 + 2.f*uv*w1v*QX + w1v*w1v*Q2;
        sv += __shfl_xor(sv, 32);
        sq += __shfl_xor(sq, 32);
        dt += __shfl_xor(dt, 32);
        const float mu = sv * (1.f/64.f);
        const float vv = sq * (1.f/64.f) - mu*mu;
        const float rs = __builtin_amdgcn_rsqf(vv + 1e-5f);
        const float o = fmaf(rs, dt - mu*C1, outc);
        if (lane < 32) out[p0 + lane] = o;
        // rotate pipeline registers
        if (it + 1 < ITERS) { fb0 = nfb0; fb1 = nfb1; }
    }
}

extern "C" void kernel_launch(void* const* d_in, const int* in_sizes, int n_in,
                              void* d_out, int out_size, void* d_ws, size_t ws_size,
                              hipStream_t stream)
{
    const float* coords = (const float*)d_in[0];
    const float* cost   = (const float*)d_in[1];
    const float* lscale = (const float*)d_in[2];
    const float* W1     = (const float*)d_in[3];
    const float* b1     = (const float*)d_in[4];
    const float* W2     = (const float*)d_in[5];
    const float* b2     = (const float*)d_in[6];
    const float* fg     = (const float*)d_in[7];
    const float* fb     = (const float*)d_in[8];
    const float* Wg1    = (const float*)d_in[9];
    const float* bg1    = (const float*)d_in[10];
    const float* Wg2    = (const float*)d_in[11];
    const float* bg2    = (const float*)d_in[12];
    const float* gt     = (const float*)d_in[13];
    const float* lng    = (const float*)d_in[14];
    const float* lnb    = (const float*)d_in[15];
    const float* Wo     = (const float*)d_in[16];
    const float* bo     = (const float*)d_in[17];
    float* out = (float*)d_out;

    prep_kernel<<<20, 256, 0, stream>>>(W1, b1, W2, b2, fg, fb, Wg1, bg1, Wg2, lng, lnb, Wo);
    fused_kernel<<<BLOCKS, 256, 0, stream>>>(coords, cost, lscale, bg2, gt, bo, out);
}